// Round 8
// baseline (1678.971 us; speedup 1.0000x reference)
//
#include <hip/hip_runtime.h>

// Relation_5841155522972 — talking-heads attention, straight-through hard select.
// out[b,i,h*64+d] = v[b, argmax_j n[b,h,i,j], h*64+d],
// n = LayerNorm_h( softmax_j(QK^T/32) mixed by Wt ).
//
// R13: two-tier. R12's fallback fired -> ws_size < 312 MB. Since the stream
// is in-order, the E-matrix only needs to exist for ONE batch at a time:
// per-b pairs (stats_v6b -> select_v11b) share a single 64 MB Sp buffer
// (total ws 120 MB). Select's 8.6-GFLOP dot recompute is replaced by a
// streamed, L3-resident E read. Fallback (ws < 120 MB): select_v12 = v5 with
// h-PAIR dot (wave-uniform hA,hB; 4 VMEM + 32 FMA per d -> 2x in-flight
// loads; dot-phase VGPR has headroom since mix's ~128 is the binding max
// under the measured pool-256 model: waves/SIMD = floor(256/VGPR)).
//  K1   qkv_gemm                      : unchanged fp32 GEMM.
//  K2a  attn_stats_v6b / attn_stats_v5: per-b E-store / fallback.
//  K2b  attn_select_v11b / _v12       : E-stream / h-pair-ILP dot.
//  K2c  gather_v4                     : unchanged.

#define FMA4(cc, av, bv) \
  cc.x = fmaf(av, bv.x, cc.x); cc.y = fmaf(av, bv.y, cc.y); \
  cc.z = fmaf(av, bv.z, cc.z); cc.w = fmaf(av, bv.w, cc.w);

__global__ __launch_bounds__(256) void qkv_gemm(
    const float* __restrict__ X, const float* __restrict__ Wq,
    const float* __restrict__ Wkv, float* __restrict__ qT,
    float* __restrict__ kT, float* __restrict__ V)
{
  __shared__ __align__(16) float As[16 * 132];
  __shared__ __align__(16) float Bs[16 * 132];
  __shared__ __align__(16) float tb[128 * 32];

  const int t  = threadIdx.x;
  const int bn = blockIdx.x;
  const int bm = blockIdx.y;
  const int m0 = bm * 128, n0 = bn * 128;
  const int ty = t >> 4, tx = t & 15;

  const float* Wbase = (n0 < 1024) ? Wq : Wkv;
  const int nw0 = (n0 < 1024) ? n0 : (n0 - 1024);

  float4 c2[8][2];
#pragma unroll
  for (int a = 0; a < 8; a++) {
    c2[a][0] = make_float4(0.f, 0.f, 0.f, 0.f);
    c2[a][1] = make_float4(0.f, 0.f, 0.f, 0.f);
  }

  const int lr = t >> 1;
  const int lh = t & 1;

  const float4* As4 = (const float4*)As;
  const float4* Bs4 = (const float4*)Bs;

  for (int kb = 0; kb < 64; kb++) {
    const int k0 = kb * 16;
    __syncthreads();
#pragma unroll
    for (int s = 0; s < 2; s++) {
      const int kk = lh * 8 + s * 4;
      float4 av = *(const float4*)&X[(size_t)(m0 + lr) * 1024 + k0 + kk];
      float4 bv = *(const float4*)&Wbase[(size_t)(nw0 + lr) * 1024 + k0 + kk];
      As[(kk + 0) * 132 + lr] = av.x;
      As[(kk + 1) * 132 + lr] = av.y;
      As[(kk + 2) * 132 + lr] = av.z;
      As[(kk + 3) * 132 + lr] = av.w;
      Bs[(kk + 0) * 132 + lr] = bv.x;
      Bs[(kk + 1) * 132 + lr] = bv.y;
      Bs[(kk + 2) * 132 + lr] = bv.z;
      Bs[(kk + 3) * 132 + lr] = bv.w;
    }
    __syncthreads();
#pragma unroll
    for (int kk = 0; kk < 16; kk++) {
      float4 a0 = As4[kk * 33 + ty * 2];
      float4 a1 = As4[kk * 33 + ty * 2 + 1];
      float4 b0 = Bs4[kk * 33 + tx];
      float4 b1 = Bs4[kk * 33 + 16 + tx];
      FMA4(c2[0][0], a0.x, b0); FMA4(c2[0][1], a0.x, b1);
      FMA4(c2[1][0], a0.y, b0); FMA4(c2[1][1], a0.y, b1);
      FMA4(c2[2][0], a0.z, b0); FMA4(c2[2][1], a0.z, b1);
      FMA4(c2[3][0], a0.w, b0); FMA4(c2[3][1], a0.w, b1);
      FMA4(c2[4][0], a1.x, b0); FMA4(c2[4][1], a1.x, b1);
      FMA4(c2[5][0], a1.y, b0); FMA4(c2[5][1], a1.y, b1);
      FMA4(c2[6][0], a1.z, b0); FMA4(c2[6][1], a1.z, b1);
      FMA4(c2[7][0], a1.w, b0); FMA4(c2[7][1], a1.w, b1);
    }
  }

  if (n0 >= 2048) {
    const int nv0 = n0 - 2048;
#pragma unroll
    for (int a = 0; a < 8; a++) {
      *(float4*)&V[(size_t)(m0 + ty * 8 + a) * 1024 + nv0 + tx * 4]      = c2[a][0];
      *(float4*)&V[(size_t)(m0 + ty * 8 + a) * 1024 + nv0 + 64 + tx * 4] = c2[a][1];
    }
    return;
  }

  float* T = (n0 < 1024) ? qT : kT;
  const int nt0 = (n0 < 1024) ? n0 : (n0 - 1024);
  const int bB = m0 >> 10;
  const int i0 = m0 & 1023;
#pragma unroll
  for (int r = 0; r < 4; r++) {
    __syncthreads();
    if ((tx >> 3) == (r & 1)) {
      const int c0 = (tx & 7) * 4;
#pragma unroll
      for (int a = 0; a < 8; a++) {
        const int m = ty * 8 + a;
        float4 val = c2[a][r >> 1];
        tb[m * 32 + ((c0 + 0 + m) & 31)] = val.x;
        tb[m * 32 + ((c0 + 1 + m) & 31)] = val.y;
        tb[m * 32 + ((c0 + 2 + m) & 31)] = val.z;
        tb[m * 32 + ((c0 + 3 + m) & 31)] = val.w;
      }
    }
    __syncthreads();
    const int nl = t >> 3, mq = t & 7;
    float* Trow = T + (size_t)(bB * 1024 + nt0 + (r >> 1) * 64 + (r & 1) * 32 + nl) * 1024 + i0;
#pragma unroll
    for (int l = 0; l < 4; l++) {
      const int mb = (l * 8 + mq) * 4;
      float4 o;
      o.x = tb[(mb + 0) * 32 + ((nl + mb + 0) & 31)];
      o.y = tb[(mb + 1) * 32 + ((nl + mb + 1) & 31)];
      o.z = tb[(mb + 2) * 32 + ((nl + mb + 2) & 31)];
      o.w = tb[(mb + 3) * 32 + ((nl + mb + 3) & 31)];
      *(float4*)(Trow + mb) = o;
    }
  }
}

// ---------------------------------------------------------------------------
// K2a v5 (fallback): no-LDS stats, all 4 batches. (unchanged)
// ---------------------------------------------------------------------------
__global__ __launch_bounds__(256) void attn_stats_v5(
    const float* __restrict__ qT, const float* __restrict__ kT,
    float* __restrict__ Mm, float* __restrict__ Ml)
{
  const int t  = threadIdx.x;
  const int bx = blockIdx.x;
  const int b  = bx >> 8;
  const int it = (bx >> 3) & 31;
  const int js = bx & 7;
  const int wv = t >> 6;
  const int l  = t & 63;
  const int ih = l >> 5;
  const int jg = l & 31;
  const int i0w = __builtin_amdgcn_readfirstlane(it * 32 + wv * 8);
  const int iq = i0w + ih * 4;
  const int jq = js * 128 + jg * 4;

  const float scale = 0.03125f;

  for (int h = 0; h < 16; h++) {
    const size_t base = (size_t)(b * 1024 + h * 64) * 1024;
    float4 acc[4];
#pragma unroll
    for (int ii = 0; ii < 4; ii++) acc[ii] = make_float4(0.f, 0.f, 0.f, 0.f);

#pragma unroll 4
    for (int d = 0; d < 64; d++) {
      const float4 qv = *(const float4*)(qT + base + (size_t)d * 1024 + iq);
      const float4 kv = *(const float4*)(kT + base + (size_t)d * 1024 + jq);
      FMA4(acc[0], qv.x, kv);
      FMA4(acc[1], qv.y, kv);
      FMA4(acc[2], qv.z, kv);
      FMA4(acc[3], qv.w, kv);
    }

#pragma unroll
    for (int ii = 0; ii < 4; ii++) {
      const float s0 = acc[ii].x * scale;
      const float s1 = acc[ii].y * scale;
      const float s2 = acc[ii].z * scale;
      const float s3 = acc[ii].w * scale;
      float mx = fmaxf(fmaxf(s0, s1), fmaxf(s2, s3));
      mx = fmaxf(mx, __shfl_xor(mx, 1));
      mx = fmaxf(mx, __shfl_xor(mx, 2));
      mx = fmaxf(mx, __shfl_xor(mx, 4));
      mx = fmaxf(mx, __shfl_xor(mx, 8));
      mx = fmaxf(mx, __shfl_xor(mx, 16));
      float ss = __expf(s0 - mx) + __expf(s1 - mx) +
                 __expf(s2 - mx) + __expf(s3 - mx);
      ss += __shfl_xor(ss, 1);
      ss += __shfl_xor(ss, 2);
      ss += __shfl_xor(ss, 4);
      ss += __shfl_xor(ss, 8);
      ss += __shfl_xor(ss, 16);
      if (jg == ii) {
        const int idx = (((b * 16 + h) * 1024 + iq + ii) << 3) + js;
        Mm[idx] = mx;
        Ml[idx] = ss;
      }
    }
  }
}

// ---------------------------------------------------------------------------
// K2a v6b: per-batch stats + E-store. grid = it(32) x js(8) = 256 blocks.
// Identical dot/stats math; stores E = exp(s - m_slice) to Sp[h][i][j]
// (16M floats = 64 MB), coalesced 512B per wave row.
// ---------------------------------------------------------------------------
__global__ __launch_bounds__(256) void attn_stats_v6b(
    const float* __restrict__ qT, const float* __restrict__ kT,
    float* __restrict__ Mm, float* __restrict__ Ml,
    float* __restrict__ Sp, int b)
{
  const int t  = threadIdx.x;
  const int bx = blockIdx.x;
  const int it = bx >> 3;
  const int js = bx & 7;
  const int wv = t >> 6;
  const int l  = t & 63;
  const int ih = l >> 5;
  const int jg = l & 31;
  const int i0w = __builtin_amdgcn_readfirstlane(it * 32 + wv * 8);
  const int iq = i0w + ih * 4;
  const int jq = js * 128 + jg * 4;

  const float scale = 0.03125f;

  for (int h = 0; h < 16; h++) {
    const size_t base = (size_t)(b * 1024 + h * 64) * 1024;
    float4 acc[4];
#pragma unroll
    for (int ii = 0; ii < 4; ii++) acc[ii] = make_float4(0.f, 0.f, 0.f, 0.f);

#pragma unroll 4
    for (int d = 0; d < 64; d++) {
      const float4 qv = *(const float4*)(qT + base + (size_t)d * 1024 + iq);
      const float4 kv = *(const float4*)(kT + base + (size_t)d * 1024 + jq);
      FMA4(acc[0], qv.x, kv);
      FMA4(acc[1], qv.y, kv);
      FMA4(acc[2], qv.z, kv);
      FMA4(acc[3], qv.w, kv);
    }

#pragma unroll
    for (int ii = 0; ii < 4; ii++) {
      const float s0 = acc[ii].x * scale;
      const float s1 = acc[ii].y * scale;
      const float s2 = acc[ii].z * scale;
      const float s3 = acc[ii].w * scale;
      float mx = fmaxf(fmaxf(s0, s1), fmaxf(s2, s3));
      mx = fmaxf(mx, __shfl_xor(mx, 1));
      mx = fmaxf(mx, __shfl_xor(mx, 2));
      mx = fmaxf(mx, __shfl_xor(mx, 4));
      mx = fmaxf(mx, __shfl_xor(mx, 8));
      mx = fmaxf(mx, __shfl_xor(mx, 16));
      const float e0 = __expf(s0 - mx);
      const float e1 = __expf(s1 - mx);
      const float e2 = __expf(s2 - mx);
      const float e3 = __expf(s3 - mx);
      *(float4*)&Sp[((size_t)(h * 1024) + iq + ii) * 1024 + jq] =
          make_float4(e0, e1, e2, e3);
      float ss = e0 + e1 + e2 + e3;
      ss += __shfl_xor(ss, 1);
      ss += __shfl_xor(ss, 2);
      ss += __shfl_xor(ss, 4);
      ss += __shfl_xor(ss, 8);
      ss += __shfl_xor(ss, 16);
      if (jg == ii) {
        const int idx = (((b * 16 + h) * 1024 + iq + ii) << 3) + js;
        Mm[idx] = mx;
        Ml[idx] = ss;
      }
    }
  }
}

// packed key: monotone(float) << 32 | (1023 - j); atomicMax == (>, tie: min j)
__device__ inline unsigned long long mkkey(float v, int j) {
  unsigned u = __float_as_uint(v);
  u = (u & 0x80000000u) ? ~u : (u | 0x80000000u);
  return ((unsigned long long)u << 32) | (unsigned)(1023 - j);
}

// ---------------------------------------------------------------------------
// K2b v12 (fallback): v5 select with h-PAIR dot. 2 rounds; round r covers
// wave-uniform hA = wv*4 + 2r and hB = hA+1: 4 VMEM + 32 FMA per d
// (2x in-flight loads vs v5). unroll 2 bounds load regs; mix phase (the
// VGPR ceiling ~128) unchanged, so waves/SIMD stays 2 (pool-256 model).
// ---------------------------------------------------------------------------
__global__ __launch_bounds__(256) void attn_select_v12(
    const float* __restrict__ qT, const float* __restrict__ kT,
    const float* __restrict__ Mm, const float* __restrict__ Ml,
    const float* __restrict__ Wt, const float* __restrict__ ln_g,
    const float* __restrict__ ln_b, unsigned long long* __restrict__ HiKey)
{
  __shared__ __align__(16) float smem[64 * 271 + 512];
  float* ptile = smem;
  float* mred  = smem + 64 * 271;
  float* rred  = mred + 256;

  const int t  = threadIdx.x;
  const int bx = blockIdx.x;
  const int b  = bx >> 10;
  const int it = (bx >> 4) & 63;
  const int js = bx & 15;
  const int i0 = it << 4;
  const int j0 = js << 6;

  const float scale = 0.03125f;

  {
    const int base = (((b * 16 + (t >> 4)) * 1024 + i0 + (t & 15)) << 3);
    const float4 ma = *(const float4*)&Mm[base];
    const float4 mb = *(const float4*)&Mm[base + 4];
    const float4 la = *(const float4*)&Ml[base];
    const float4 lb = *(const float4*)&Ml[base + 4];
    float M = fmaxf(fmaxf(fmaxf(ma.x, ma.y), fmaxf(ma.z, ma.w)),
                    fmaxf(fmaxf(mb.x, mb.y), fmaxf(mb.z, mb.w)));
    float L = la.x * __expf(ma.x - M) + la.y * __expf(ma.y - M) +
              la.z * __expf(ma.z - M) + la.w * __expf(ma.w - M) +
              lb.x * __expf(mb.x - M) + lb.y * __expf(mb.y - M) +
              lb.z * __expf(mb.z - M) + lb.w * __expf(mb.w - M);
    mred[t] = M;
    rred[t] = 1.0f / L;
  }
  __syncthreads();

  const int wv = t >> 6;
  const int l  = t & 63;
  const int jq = l & 15;
  const int ig = l >> 4;
  const int iq = i0 + ig * 4;
  const int jcol = j0 + jq * 4;

#pragma unroll
  for (int r = 0; r < 2; r++) {
    const int hA = wv * 4 + r * 2;
    const size_t baseA = (size_t)(b * 1024 + hA * 64) * 1024;
    const size_t baseB = baseA + (size_t)64 * 1024;
    float4 accA[4], accB[4];
#pragma unroll
    for (int ii = 0; ii < 4; ii++) {
      accA[ii] = make_float4(0.f, 0.f, 0.f, 0.f);
      accB[ii] = make_float4(0.f, 0.f, 0.f, 0.f);
    }

#pragma unroll 2
    for (int d = 0; d < 64; d++) {
      const float4 qA = *(const float4*)(qT + baseA + (size_t)d * 1024 + iq);
      const float4 kA = *(const float4*)(kT + baseA + (size_t)d * 1024 + jcol);
      const float4 qB = *(const float4*)(qT + baseB + (size_t)d * 1024 + iq);
      const float4 kB = *(const float4*)(kT + baseB + (size_t)d * 1024 + jcol);
      FMA4(accA[0], qA.x, kA);
      FMA4(accA[1], qA.y, kA);
      FMA4(accA[2], qA.z, kA);
      FMA4(accA[3], qA.w, kA);
      FMA4(accB[0], qB.x, kB);
      FMA4(accB[1], qB.y, kB);
      FMA4(accB[2], qB.z, kB);
      FMA4(accB[3], qB.w, kB);
    }

#pragma unroll
    for (int hs = 0; hs < 2; hs++) {
      const int h = hA + hs;
      const float4* acc = hs ? accB : accA;
      const int hrot = (h + jq) & 15;
#pragma unroll
      for (int ii = 0; ii < 4; ii++) {
        const int iL = ig * 4 + ii;
        const float m = mred[h * 16 + iL];
        const float rr = rred[h * 16 + iL];
        const float a4[4] = {acc[ii].x, acc[ii].y, acc[ii].z, acc[ii].w};
#pragma unroll
        for (int jj = 0; jj < 4; jj++) {
          const int j = jq * 4 + jj;
          const float p = __expf(a4[jj] * scale - m) * rr;
          ptile[j * 271 + iL * 17 + hrot] = p;
        }
      }
    }
  }
  __syncthreads();

  const int i2 = t >> 4;
  const int g  = (t >> 2) & 3;
  const int hq = t & 3;

  float wtr[4][16], gr[4], br[4];
#pragma unroll
  for (int a = 0; a < 4; a++) {
#pragma unroll
    for (int h2 = 0; h2 < 16; h2++) wtr[a][h2] = Wt[(hq * 4 + a) * 16 + h2];
    gr[a] = ln_g[hq * 4 + a];
    br[a] = ln_b[hq * 4 + a];
  }
  float bv[4]; int bix[4];
#pragma unroll
  for (int a = 0; a < 4; a++) { bv[a] = -1e30f; bix[a] = 0; }

#pragma unroll
  for (int jj = 0; jj < 16; jj++) {
    const int j = g * 16 + jj;
    const int jr = j >> 2;
    float pv[16];
#pragma unroll
    for (int h2 = 0; h2 < 16; h2++)
      pv[h2] = ptile[j * 271 + i2 * 17 + ((h2 + jr) & 15)];
    float mix[4];
#pragma unroll
    for (int a = 0; a < 4; a++) {
      float s0 = 0.f;
#pragma unroll
      for (int h2 = 0; h2 < 16; h2++) s0 = fmaf(pv[h2], wtr[a][h2], s0);
      mix[a] = s0;
    }
    float s1 = mix[0] + mix[1] + mix[2] + mix[3];
    s1 += __shfl_xor(s1, 1);
    s1 += __shfl_xor(s1, 2);
    const float mu = s1 * 0.0625f;
    float s2 = 0.f;
#pragma unroll
    for (int a = 0; a < 4; a++) { const float dd = mix[a] - mu; s2 = fmaf(dd, dd, s2); }
    s2 += __shfl_xor(s2, 1);
    s2 += __shfl_xor(s2, 2);
    const float rstd = rsqrtf(s2 * 0.0625f + 1e-5f);
    const int jg2 = j0 + j;
#pragma unroll
    for (int a = 0; a < 4; a++) {
      const float nv = (mix[a] - mu) * rstd * gr[a] + br[a];
      if (nv > bv[a]) { bv[a] = nv; bix[a] = jg2; }
    }
  }

#pragma unroll
  for (int a = 0; a < 4; a++) {
    float v = bv[a]; int ix = bix[a];
    {
      const float ov = __shfl_xor(v, 4);
      const int oi = __shfl_xor(ix, 4);
      if (ov > v || (ov == v && oi < ix)) { v = ov; ix = oi; }
    }
    {
      const float ov = __shfl_xor(v, 8);
      const int oi = __shfl_xor(ix, 8);
      if (ov > v || (ov == v && oi < ix)) { v = ov; ix = oi; }
    }
    bv[a] = v; bix[a] = ix;
  }

  if (g == 0) {
#pragma unroll
    for (int a = 0; a < 4; a++) {
      const int cell = (b * 16 + hq * 4 + a) * 1024 + i0 + i2;
      atomicMax(&HiKey[cell], mkkey(bv[a], bix[a]));
    }
  }
}

// ---------------------------------------------------------------------------
// K2b v11b: per-batch NO-dot select. grid = it(64) x js(16) = 1024 blocks.
// Prologue: M,L merge + block-slice factor f = exp(m_si - M)/L (si = js>>1).
// E-stream: p = E*f from Sp (L3-resident, written by the just-prior stats).
// Mix/LN/argmax: v5 verbatim.
// ---------------------------------------------------------------------------
__global__ __launch_bounds__(256) void attn_select_v11b(
    const float* __restrict__ Sp,
    const float* __restrict__ Mm, const float* __restrict__ Ml,
    const float* __restrict__ Wt, const float* __restrict__ ln_g,
    const float* __restrict__ ln_b, unsigned long long* __restrict__ HiKey,
    int b)
{
  __shared__ __align__(16) float smem[64 * 271 + 256];
  float* ptile = smem;                 // j*271 + i_local*17 + hrot
  float* fred  = smem + 64 * 271;      // [h*16 + i_local] = exp(m_si - M)/L

  const int t  = threadIdx.x;
  const int bx = blockIdx.x;
  const int it = bx >> 4;
  const int js = bx & 15;
  const int i0 = it << 4;
  const int j0 = js << 6;

  // prologue: merge-8 stats + block-slice factor (t == h*16 + i_local)
  {
    const int base = (((b * 16 + (t >> 4)) * 1024 + i0 + (t & 15)) << 3);
    const float4 ma = *(const float4*)&Mm[base];
    const float4 mb = *(const float4*)&Mm[base + 4];
    const float4 la = *(const float4*)&Ml[base];
    const float4 lb = *(const float4*)&Ml[base + 4];
    float M = fmaxf(fmaxf(fmaxf(ma.x, ma.y), fmaxf(ma.z, ma.w)),
                    fmaxf(fmaxf(mb.x, mb.y), fmaxf(mb.z, mb.w)));
    float L = la.x * __expf(ma.x - M) + la.y * __expf(ma.y - M) +
              la.z * __expf(ma.z - M) + la.w * __expf(ma.w - M) +
              lb.x * __expf(mb.x - M) + lb.y * __expf(mb.y - M) +
              lb.z * __expf(mb.z - M) + lb.w * __expf(mb.w - M);
    const int si = js >> 1;               // block's 128-j stats slice
    const float4 mv = (si & 4) ? mb : ma;
    const int s2 = si & 3;
    const float msl = (s2 == 0) ? mv.x : (s2 == 1) ? mv.y
                    : (s2 == 2) ? mv.z : mv.w;
    fred[t] = __expf(msl - M) / L;
  }
  __syncthreads();

  // E-stream phase: p = E * f -> rotated ptile
#pragma unroll
  for (int rr = 0; rr < 8; rr++) {
    const int rowid = rr * 32 + (t >> 3);   // h*16 + iL
    const int h  = rowid >> 4;
    const int iL = rowid & 15;
    const int jseg = (t & 7) * 8;
    const float f = fred[rowid];
    const float* src = Sp + ((size_t)(h * 1024) + i0 + iL) * 1024 + j0 + jseg;
    const float4 e0 = *(const float4*)src;
    const float4 e1 = *(const float4*)(src + 4);
    const float pv8[8] = {e0.x * f, e0.y * f, e0.z * f, e0.w * f,
                          e1.x * f, e1.y * f, e1.z * f, e1.w * f};
#pragma unroll
    for (int k = 0; k < 8; k++) {
      const int j = jseg + k;
      ptile[j * 271 + iL * 17 + ((h + (j >> 2)) & 15)] = pv8[k];
    }
  }
  __syncthreads();

  // ---- mix phase (v5 verbatim) ----
  const int i2 = t >> 4;
  const int g  = (t >> 2) & 3;
  const int hq = t & 3;

  float wtr[4][16], gr[4], br[4];
#pragma unroll
  for (int a = 0; a < 4; a++) {
#pragma unroll
    for (int h2 = 0; h2 < 16; h2++) wtr[a][h2] = Wt[(hq * 4 + a) * 16 + h2];
    gr[a] = ln_g[hq * 4 + a];
    br[a] = ln_b[hq * 4 + a];
  }
  float bv[4]; int bix[4];
#pragma unroll
  for (int a = 0; a < 4; a++) { bv[a] = -1e30f; bix[a] = 0; }

#pragma unroll
  for (int jj = 0; jj < 16; jj++) {
    const int j = g * 16 + jj;
    const int jr = j >> 2;
    float pv[16];
#pragma unroll
    for (int h2 = 0; h2 < 16; h2++)
      pv[h2] = ptile[j * 271 + i2 * 17 + ((h2 + jr) & 15)];
    float mix[4];
#pragma unroll
    for (int a = 0; a < 4; a++) {
      float s0 = 0.f;
#pragma unroll
      for (int h2 = 0; h2 < 16; h2++) s0 = fmaf(pv[h2], wtr[a][h2], s0);
      mix[a] = s0;
    }
    float s1 = mix[0] + mix[1] + mix[2] + mix[3];
    s1 += __shfl_xor(s1, 1);
    s1 += __shfl_xor(s1, 2);
    const float mu = s1 * 0.0625f;
    float s2 = 0.f;
#pragma unroll
    for (int a = 0; a < 4; a++) { const float dd = mix[a] - mu; s2 = fmaf(dd, dd, s2); }
    s2 += __shfl_xor(s2, 1);
    s2 += __shfl_xor(s2, 2);
    const float rstd = rsqrtf(s2 * 0.0625f + 1e-5f);
    const int jg2 = j0 + j;
#pragma unroll
    for (int a = 0; a < 4; a++) {
      const float nv = (mix[a] - mu) * rstd * gr[a] + br[a];
      if (nv > bv[a]) { bv[a] = nv; bix[a] = jg2; }
    }
  }

  // merge over the 4 g-lanes (ties -> smaller j), then one atomic per (a,i)
#pragma unroll
  for (int a = 0; a < 4; a++) {
    float v = bv[a]; int ix = bix[a];
    {
      const float ov = __shfl_xor(v, 4);
      const int oi = __shfl_xor(ix, 4);
      if (ov > v || (ov == v && oi < ix)) { v = ov; ix = oi; }
    }
    {
      const float ov = __shfl_xor(v, 8);
      const int oi = __shfl_xor(ix, 8);
      if (ov > v || (ov == v && oi < ix)) { v = ov; ix = oi; }
    }
    bv[a] = v; bix[a] = ix;
  }

  if (g == 0) {
#pragma unroll
    for (int a = 0; a < 4; a++) {
      const int cell = (b * 16 + hq * 4 + a) * 1024 + i0 + i2;
      atomicMax(&HiKey[cell], mkkey(bv[a], bix[a]));
    }
  }
}

// ---------------------------------------------------------------------------
// K2c: decode key -> gather V rows (unchanged).
// ---------------------------------------------------------------------------
__global__ __launch_bounds__(256) void gather_v4(
    const unsigned long long* __restrict__ HiKey, const float* __restrict__ V,
    float* __restrict__ out)
{
  const int t  = threadIdx.x;
  const int bx = blockIdx.x;
  const int b  = bx >> 6;
  const int it = bx & 63;
  const int i2 = t >> 4;
  const int h  = t & 15;

  const unsigned long long key = HiKey[(b * 16 + h) * 1024 + it * 16 + i2];
  const int j = 1023 - (int)(unsigned)(key & 0xFFFFFFFFull);

  const float* vs = V + (size_t)(b * 1024 + j) * 1024 + h * 64;
  float* dst = out + (size_t)(b * 1024 + it * 16 + i2) * 1024 + h * 64;
#pragma unroll
  for (int w = 0; w < 16; w++)
    *(float4*)(dst + w * 4) = *(const float4*)(vs + w * 4);
}

extern "C" void kernel_launch(void* const* d_in, const int* in_sizes, int n_in,
                              void* d_out, int out_size, void* d_ws, size_t ws_size,
                              hipStream_t stream) {
  const float* x   = (const float*)d_in[0];
  const float* Wq  = (const float*)d_in[1];
  const float* Wkv = (const float*)d_in[2];
  const float* Wt  = (const float*)d_in[3];
  const float* lng = (const float*)d_in[4];
  const float* lnb = (const float*)d_in[5];
  float* out = (float*)d_out;
  float* ws  = (float*)d_ws;
  float* qT = ws;                                     // 4M f
  float* kT = ws + (size_t)4 * 1024 * 1024;           // 4M f
  float* V  = ws + (size_t)8 * 1024 * 1024;           // 4M f
  float* Mm = ws + (size_t)12 * 1024 * 1024;          // 512K f
  float* Ml = Mm + 524288;                            // 512K f
  unsigned long long* HiKey =
      (unsigned long long*)(ws + (size_t)13 * 1024 * 1024);  // 64K x 8B
  float* Sp = ws + (size_t)14 * 1024 * 1024;          // 16M f (64 MB, per-b)

  // B-path needs (14 + 16)M floats = 120 MB of workspace.
  const size_t NEED = (size_t)30 * 1024 * 1024 * 4;
  const bool big_ws = (ws_size >= NEED);

  hipLaunchKernelGGL(qkv_gemm, dim3(24, 32), dim3(256), 0, stream,
                     x, Wq, Wkv, qT, kT, V);
  hipMemsetAsync(HiKey, 0, (size_t)65536 * 8, stream);
  if (big_ws) {
    // in-order stream: one 64 MB Sp buffer, reused across the 4 batches
    for (int b = 0; b < 4; b++) {
      hipLaunchKernelGGL(attn_stats_v6b, dim3(256), dim3(256), 0, stream,
                         qT, kT, Mm, Ml, Sp, b);
      hipLaunchKernelGGL(attn_select_v11b, dim3(1024), dim3(256), 0, stream,
                         Sp, Mm, Ml, Wt, lng, lnb, HiKey, b);
    }
  } else {
    hipLaunchKernelGGL(attn_stats_v5, dim3(1024), dim3(256), 0, stream,
                       qT, kT, Mm, Ml);
    hipLaunchKernelGGL(attn_select_v12, dim3(4096), dim3(256), 0, stream,
                       qT, kT, Mm, Ml, Wt, lng, lnb, HiKey);
  }
  hipLaunchKernelGGL(gather_v4, dim3(256), dim3(256), 0, stream,
                     HiKey, V, out);
}

// Round 9
// 972.671 us; speedup vs baseline: 1.7261x; 1.7261x over previous
//
#include <hip/hip_runtime.h>

// Relation_5841155522972 — talking-heads attention, straight-through hard select.
// out[b,i,h*64+d] = v[b, argmax_j n[b,h,i,j], h*64+d],
// n = LayerNorm_h( softmax_j(QK^T/32) mixed by Wt ).
//
// R14: A-path only. R13's E-store B-path regressed 1679us: per-batch stats
// (256 blocks) is latency-bound -> wall-time grid-invariant -> 4x serial cost.
// [Closed: E-store/dataflow; occupancy axis (R6-R11).] This round benches the
// h-pair ILP select that R13's fallback never ran:
//  K2b attn_select_v12: v5 with wave-uniform h-PAIR dot. Per d: 4 VMEM +
//  32 FMA (2x in-flight loads vs v5's 2+16 at 44% VALUBusy / 2 waves/SIMD).
//  Epilogue duplicated per head (no runtime-indexed reg arrays). Mix/LN/
//  argmax v5-verbatim; VGPR expected 128 (mix is the ceiling).
//  K1 qkv_gemm, K2a attn_stats_v5, K2c gather_v4: unchanged.
// ws: 52.5 MB.

#define FMA4(cc, av, bv) \
  cc.x = fmaf(av, bv.x, cc.x); cc.y = fmaf(av, bv.y, cc.y); \
  cc.z = fmaf(av, bv.z, cc.z); cc.w = fmaf(av, bv.w, cc.w);

__global__ __launch_bounds__(256) void qkv_gemm(
    const float* __restrict__ X, const float* __restrict__ Wq,
    const float* __restrict__ Wkv, float* __restrict__ qT,
    float* __restrict__ kT, float* __restrict__ V)
{
  __shared__ __align__(16) float As[16 * 132];
  __shared__ __align__(16) float Bs[16 * 132];
  __shared__ __align__(16) float tb[128 * 32];

  const int t  = threadIdx.x;
  const int bn = blockIdx.x;
  const int bm = blockIdx.y;
  const int m0 = bm * 128, n0 = bn * 128;
  const int ty = t >> 4, tx = t & 15;

  const float* Wbase = (n0 < 1024) ? Wq : Wkv;
  const int nw0 = (n0 < 1024) ? n0 : (n0 - 1024);

  float4 c2[8][2];
#pragma unroll
  for (int a = 0; a < 8; a++) {
    c2[a][0] = make_float4(0.f, 0.f, 0.f, 0.f);
    c2[a][1] = make_float4(0.f, 0.f, 0.f, 0.f);
  }

  const int lr = t >> 1;
  const int lh = t & 1;

  const float4* As4 = (const float4*)As;
  const float4* Bs4 = (const float4*)Bs;

  for (int kb = 0; kb < 64; kb++) {
    const int k0 = kb * 16;
    __syncthreads();
#pragma unroll
    for (int s = 0; s < 2; s++) {
      const int kk = lh * 8 + s * 4;
      float4 av = *(const float4*)&X[(size_t)(m0 + lr) * 1024 + k0 + kk];
      float4 bv = *(const float4*)&Wbase[(size_t)(nw0 + lr) * 1024 + k0 + kk];
      As[(kk + 0) * 132 + lr] = av.x;
      As[(kk + 1) * 132 + lr] = av.y;
      As[(kk + 2) * 132 + lr] = av.z;
      As[(kk + 3) * 132 + lr] = av.w;
      Bs[(kk + 0) * 132 + lr] = bv.x;
      Bs[(kk + 1) * 132 + lr] = bv.y;
      Bs[(kk + 2) * 132 + lr] = bv.z;
      Bs[(kk + 3) * 132 + lr] = bv.w;
    }
    __syncthreads();
#pragma unroll
    for (int kk = 0; kk < 16; kk++) {
      float4 a0 = As4[kk * 33 + ty * 2];
      float4 a1 = As4[kk * 33 + ty * 2 + 1];
      float4 b0 = Bs4[kk * 33 + tx];
      float4 b1 = Bs4[kk * 33 + 16 + tx];
      FMA4(c2[0][0], a0.x, b0); FMA4(c2[0][1], a0.x, b1);
      FMA4(c2[1][0], a0.y, b0); FMA4(c2[1][1], a0.y, b1);
      FMA4(c2[2][0], a0.z, b0); FMA4(c2[2][1], a0.z, b1);
      FMA4(c2[3][0], a0.w, b0); FMA4(c2[3][1], a0.w, b1);
      FMA4(c2[4][0], a1.x, b0); FMA4(c2[4][1], a1.x, b1);
      FMA4(c2[5][0], a1.y, b0); FMA4(c2[5][1], a1.y, b1);
      FMA4(c2[6][0], a1.z, b0); FMA4(c2[6][1], a1.z, b1);
      FMA4(c2[7][0], a1.w, b0); FMA4(c2[7][1], a1.w, b1);
    }
  }

  if (n0 >= 2048) {
    const int nv0 = n0 - 2048;
#pragma unroll
    for (int a = 0; a < 8; a++) {
      *(float4*)&V[(size_t)(m0 + ty * 8 + a) * 1024 + nv0 + tx * 4]      = c2[a][0];
      *(float4*)&V[(size_t)(m0 + ty * 8 + a) * 1024 + nv0 + 64 + tx * 4] = c2[a][1];
    }
    return;
  }

  float* T = (n0 < 1024) ? qT : kT;
  const int nt0 = (n0 < 1024) ? n0 : (n0 - 1024);
  const int bB = m0 >> 10;
  const int i0 = m0 & 1023;
#pragma unroll
  for (int r = 0; r < 4; r++) {
    __syncthreads();
    if ((tx >> 3) == (r & 1)) {
      const int c0 = (tx & 7) * 4;
#pragma unroll
      for (int a = 0; a < 8; a++) {
        const int m = ty * 8 + a;
        float4 val = c2[a][r >> 1];
        tb[m * 32 + ((c0 + 0 + m) & 31)] = val.x;
        tb[m * 32 + ((c0 + 1 + m) & 31)] = val.y;
        tb[m * 32 + ((c0 + 2 + m) & 31)] = val.z;
        tb[m * 32 + ((c0 + 3 + m) & 31)] = val.w;
      }
    }
    __syncthreads();
    const int nl = t >> 3, mq = t & 7;
    float* Trow = T + (size_t)(bB * 1024 + nt0 + (r >> 1) * 64 + (r & 1) * 32 + nl) * 1024 + i0;
#pragma unroll
    for (int l = 0; l < 4; l++) {
      const int mb = (l * 8 + mq) * 4;
      float4 o;
      o.x = tb[(mb + 0) * 32 + ((nl + mb + 0) & 31)];
      o.y = tb[(mb + 1) * 32 + ((nl + mb + 1) & 31)];
      o.z = tb[(mb + 2) * 32 + ((nl + mb + 2) & 31)];
      o.w = tb[(mb + 3) * 32 + ((nl + mb + 3) & 31)];
      *(float4*)(Trow + mb) = o;
    }
  }
}

// ---------------------------------------------------------------------------
// K2a v5: no-LDS stats, float4 x float4 register tile. (unchanged)
// ---------------------------------------------------------------------------
__global__ __launch_bounds__(256) void attn_stats_v5(
    const float* __restrict__ qT, const float* __restrict__ kT,
    float* __restrict__ Mm, float* __restrict__ Ml)
{
  const int t  = threadIdx.x;
  const int bx = blockIdx.x;
  const int b  = bx >> 8;
  const int it = (bx >> 3) & 31;
  const int js = bx & 7;
  const int wv = t >> 6;
  const int l  = t & 63;
  const int ih = l >> 5;
  const int jg = l & 31;
  const int i0w = __builtin_amdgcn_readfirstlane(it * 32 + wv * 8);
  const int iq = i0w + ih * 4;
  const int jq = js * 128 + jg * 4;

  const float scale = 0.03125f;

  for (int h = 0; h < 16; h++) {
    const size_t base = (size_t)(b * 1024 + h * 64) * 1024;
    float4 acc[4];
#pragma unroll
    for (int ii = 0; ii < 4; ii++) acc[ii] = make_float4(0.f, 0.f, 0.f, 0.f);

#pragma unroll 4
    for (int d = 0; d < 64; d++) {
      const float4 qv = *(const float4*)(qT + base + (size_t)d * 1024 + iq);
      const float4 kv = *(const float4*)(kT + base + (size_t)d * 1024 + jq);
      FMA4(acc[0], qv.x, kv);
      FMA4(acc[1], qv.y, kv);
      FMA4(acc[2], qv.z, kv);
      FMA4(acc[3], qv.w, kv);
    }

#pragma unroll
    for (int ii = 0; ii < 4; ii++) {
      const float s0 = acc[ii].x * scale;
      const float s1 = acc[ii].y * scale;
      const float s2 = acc[ii].z * scale;
      const float s3 = acc[ii].w * scale;
      float mx = fmaxf(fmaxf(s0, s1), fmaxf(s2, s3));
      mx = fmaxf(mx, __shfl_xor(mx, 1));
      mx = fmaxf(mx, __shfl_xor(mx, 2));
      mx = fmaxf(mx, __shfl_xor(mx, 4));
      mx = fmaxf(mx, __shfl_xor(mx, 8));
      mx = fmaxf(mx, __shfl_xor(mx, 16));
      float ss = __expf(s0 - mx) + __expf(s1 - mx) +
                 __expf(s2 - mx) + __expf(s3 - mx);
      ss += __shfl_xor(ss, 1);
      ss += __shfl_xor(ss, 2);
      ss += __shfl_xor(ss, 4);
      ss += __shfl_xor(ss, 8);
      ss += __shfl_xor(ss, 16);
      if (jg == ii) {
        const int idx = (((b * 16 + h) * 1024 + iq + ii) << 3) + js;
        Mm[idx] = mx;
        Ml[idx] = ss;
      }
    }
  }
}

// packed key: monotone(float) << 32 | (1023 - j); atomicMax == (>, tie: min j)
__device__ inline unsigned long long mkkey(float v, int j) {
  unsigned u = __float_as_uint(v);
  u = (u & 0x80000000u) ? ~u : (u | 0x80000000u);
  return ((unsigned long long)u << 32) | (unsigned)(1023 - j);
}

// ---------------------------------------------------------------------------
// K2b v12: v5 select with h-PAIR dot. grid = b(4) x it(64 x 16i) x
// js(16 x 64j) = 4096 blocks, 256 thr. 2 rounds; round r covers wave-uniform
// hA = wv*4 + 2r and hB = hA+1: per d, 4 VMEM + 32 FMA (2x in-flight loads
// vs v5). Epilogue duplicated per head (static reg indexing only).
// Mix/LN/argmax: v5 verbatim. Expected VGPR 128 (mix phase is the ceiling).
// ---------------------------------------------------------------------------
__global__ __launch_bounds__(256) void attn_select_v12(
    const float* __restrict__ qT, const float* __restrict__ kT,
    const float* __restrict__ Mm, const float* __restrict__ Ml,
    const float* __restrict__ Wt, const float* __restrict__ ln_g,
    const float* __restrict__ ln_b, unsigned long long* __restrict__ HiKey)
{
  __shared__ __align__(16) float smem[64 * 271 + 512];
  float* ptile = smem;
  float* mred  = smem + 64 * 271;
  float* rred  = mred + 256;

  const int t  = threadIdx.x;
  const int bx = blockIdx.x;
  const int b  = bx >> 10;
  const int it = (bx >> 4) & 63;
  const int js = bx & 15;
  const int i0 = it << 4;
  const int j0 = js << 6;

  const float scale = 0.03125f;

  {
    const int base = (((b * 16 + (t >> 4)) * 1024 + i0 + (t & 15)) << 3);
    const float4 ma = *(const float4*)&Mm[base];
    const float4 mb = *(const float4*)&Mm[base + 4];
    const float4 la = *(const float4*)&Ml[base];
    const float4 lb = *(const float4*)&Ml[base + 4];
    float M = fmaxf(fmaxf(fmaxf(ma.x, ma.y), fmaxf(ma.z, ma.w)),
                    fmaxf(fmaxf(mb.x, mb.y), fmaxf(mb.z, mb.w)));
    float L = la.x * __expf(ma.x - M) + la.y * __expf(ma.y - M) +
              la.z * __expf(ma.z - M) + la.w * __expf(ma.w - M) +
              lb.x * __expf(mb.x - M) + lb.y * __expf(mb.y - M) +
              lb.z * __expf(mb.z - M) + lb.w * __expf(mb.w - M);
    mred[t] = M;
    rred[t] = 1.0f / L;
  }
  __syncthreads();

  const int wv = t >> 6;
  const int l  = t & 63;
  const int jq = l & 15;
  const int ig = l >> 4;
  const int iq = i0 + ig * 4;
  const int jcol = j0 + jq * 4;

#pragma unroll
  for (int r = 0; r < 2; r++) {
    const int hA = wv * 4 + r * 2;
    const size_t baseA = (size_t)(b * 1024 + hA * 64) * 1024;
    const size_t baseB = baseA + (size_t)64 * 1024;
    float4 accA[4], accB[4];
#pragma unroll
    for (int ii = 0; ii < 4; ii++) {
      accA[ii] = make_float4(0.f, 0.f, 0.f, 0.f);
      accB[ii] = make_float4(0.f, 0.f, 0.f, 0.f);
    }

#pragma unroll 2
    for (int d = 0; d < 64; d++) {
      const float4 qA = *(const float4*)(qT + baseA + (size_t)d * 1024 + iq);
      const float4 kA = *(const float4*)(kT + baseA + (size_t)d * 1024 + jcol);
      const float4 qB = *(const float4*)(qT + baseB + (size_t)d * 1024 + iq);
      const float4 kB = *(const float4*)(kT + baseB + (size_t)d * 1024 + jcol);
      FMA4(accA[0], qA.x, kA);
      FMA4(accA[1], qA.y, kA);
      FMA4(accA[2], qA.z, kA);
      FMA4(accA[3], qA.w, kA);
      FMA4(accB[0], qB.x, kB);
      FMA4(accB[1], qB.y, kB);
      FMA4(accB[2], qB.z, kB);
      FMA4(accB[3], qB.w, kB);
    }

    // epilogue head A (static indexing only)
    {
      const int h = hA;
      const int hrot = (h + jq) & 15;
#pragma unroll
      for (int ii = 0; ii < 4; ii++) {
        const int iL = ig * 4 + ii;
        const float m = mred[h * 16 + iL];
        const float rr = rred[h * 16 + iL];
        const float a4[4] = {accA[ii].x, accA[ii].y, accA[ii].z, accA[ii].w};
#pragma unroll
        for (int jj = 0; jj < 4; jj++) {
          const int j = jq * 4 + jj;
          const float p = __expf(a4[jj] * scale - m) * rr;
          ptile[j * 271 + iL * 17 + hrot] = p;
        }
      }
    }
    // epilogue head B
    {
      const int h = hA + 1;
      const int hrot = (h + jq) & 15;
#pragma unroll
      for (int ii = 0; ii < 4; ii++) {
        const int iL = ig * 4 + ii;
        const float m = mred[h * 16 + iL];
        const float rr = rred[h * 16 + iL];
        const float a4[4] = {accB[ii].x, accB[ii].y, accB[ii].z, accB[ii].w};
#pragma unroll
        for (int jj = 0; jj < 4; jj++) {
          const int j = jq * 4 + jj;
          const float p = __expf(a4[jj] * scale - m) * rr;
          ptile[j * 271 + iL * 17 + hrot] = p;
        }
      }
    }
  }
  __syncthreads();

  const int i2 = t >> 4;
  const int g  = (t >> 2) & 3;
  const int hq = t & 3;

  float wtr[4][16], gr[4], br[4];
#pragma unroll
  for (int a = 0; a < 4; a++) {
#pragma unroll
    for (int h2 = 0; h2 < 16; h2++) wtr[a][h2] = Wt[(hq * 4 + a) * 16 + h2];
    gr[a] = ln_g[hq * 4 + a];
    br[a] = ln_b[hq * 4 + a];
  }
  float bv[4]; int bix[4];
#pragma unroll
  for (int a = 0; a < 4; a++) { bv[a] = -1e30f; bix[a] = 0; }

#pragma unroll
  for (int jj = 0; jj < 16; jj++) {
    const int j = g * 16 + jj;
    const int jr = j >> 2;
    float pv[16];
#pragma unroll
    for (int h2 = 0; h2 < 16; h2++)
      pv[h2] = ptile[j * 271 + i2 * 17 + ((h2 + jr) & 15)];
    float mix[4];
#pragma unroll
    for (int a = 0; a < 4; a++) {
      float s0 = 0.f;
#pragma unroll
      for (int h2 = 0; h2 < 16; h2++) s0 = fmaf(pv[h2], wtr[a][h2], s0);
      mix[a] = s0;
    }
    float s1 = mix[0] + mix[1] + mix[2] + mix[3];
    s1 += __shfl_xor(s1, 1);
    s1 += __shfl_xor(s1, 2);
    const float mu = s1 * 0.0625f;
    float s2 = 0.f;
#pragma unroll
    for (int a = 0; a < 4; a++) { const float dd = mix[a] - mu; s2 = fmaf(dd, dd, s2); }
    s2 += __shfl_xor(s2, 1);
    s2 += __shfl_xor(s2, 2);
    const float rstd = rsqrtf(s2 * 0.0625f + 1e-5f);
    const int jg2 = j0 + j;
#pragma unroll
    for (int a = 0; a < 4; a++) {
      const float nv = (mix[a] - mu) * rstd * gr[a] + br[a];
      if (nv > bv[a]) { bv[a] = nv; bix[a] = jg2; }
    }
  }

#pragma unroll
  for (int a = 0; a < 4; a++) {
    float v = bv[a]; int ix = bix[a];
    {
      const float ov = __shfl_xor(v, 4);
      const int oi = __shfl_xor(ix, 4);
      if (ov > v || (ov == v && oi < ix)) { v = ov; ix = oi; }
    }
    {
      const float ov = __shfl_xor(v, 8);
      const int oi = __shfl_xor(ix, 8);
      if (ov > v || (ov == v && oi < ix)) { v = ov; ix = oi; }
    }
    bv[a] = v; bix[a] = ix;
  }

  if (g == 0) {
#pragma unroll
    for (int a = 0; a < 4; a++) {
      const int cell = (b * 16 + hq * 4 + a) * 1024 + i0 + i2;
      atomicMax(&HiKey[cell], mkkey(bv[a], bix[a]));
    }
  }
}

// ---------------------------------------------------------------------------
// K2c: decode key -> gather V rows (unchanged).
// ---------------------------------------------------------------------------
__global__ __launch_bounds__(256) void gather_v4(
    const unsigned long long* __restrict__ HiKey, const float* __restrict__ V,
    float* __restrict__ out)
{
  const int t  = threadIdx.x;
  const int bx = blockIdx.x;
  const int b  = bx >> 6;
  const int it = bx & 63;
  const int i2 = t >> 4;
  const int h  = t & 15;

  const unsigned long long key = HiKey[(b * 16 + h) * 1024 + it * 16 + i2];
  const int j = 1023 - (int)(unsigned)(key & 0xFFFFFFFFull);

  const float* vs = V + (size_t)(b * 1024 + j) * 1024 + h * 64;
  float* dst = out + (size_t)(b * 1024 + it * 16 + i2) * 1024 + h * 64;
#pragma unroll
  for (int w = 0; w < 16; w++)
    *(float4*)(dst + w * 4) = *(const float4*)(vs + w * 4);
}

extern "C" void kernel_launch(void* const* d_in, const int* in_sizes, int n_in,
                              void* d_out, int out_size, void* d_ws, size_t ws_size,
                              hipStream_t stream) {
  const float* x   = (const float*)d_in[0];
  const float* Wq  = (const float*)d_in[1];
  const float* Wkv = (const float*)d_in[2];
  const float* Wt  = (const float*)d_in[3];
  const float* lng = (const float*)d_in[4];
  const float* lnb = (const float*)d_in[5];
  float* out = (float*)d_out;
  float* ws  = (float*)d_ws;                          // 52.5 MB used
  float* qT = ws;                                     // 4M f
  float* kT = ws + (size_t)4 * 1024 * 1024;           // 4M f
  float* V  = ws + (size_t)8 * 1024 * 1024;           // 4M f
  float* Mm = ws + (size_t)12 * 1024 * 1024;          // 512K f
  float* Ml = Mm + 524288;                            // 512K f
  unsigned long long* HiKey =
      (unsigned long long*)(ws + (size_t)13 * 1024 * 1024);  // 64K x 8B

  hipLaunchKernelGGL(qkv_gemm, dim3(24, 32), dim3(256), 0, stream,
                     x, Wq, Wkv, qT, kT, V);
  hipMemsetAsync(HiKey, 0, (size_t)65536 * 8, stream);
  hipLaunchKernelGGL(attn_stats_v5, dim3(1024), dim3(256), 0, stream,
                     qT, kT, Mm, Ml);
  hipLaunchKernelGGL(attn_select_v12, dim3(4096), dim3(256), 0, stream,
                     qT, kT, Mm, Ml, Wt, lng, lnb, HiKey);
  hipLaunchKernelGGL(gather_v4, dim3(256), dim3(256), 0, stream,
                     HiKey, V, out);
}